// Round 1
// baseline (134.777 us; speedup 1.0000x reference)
//
#include <hip/hip_runtime.h>
#include <hip/hip_bf16.h>

#define N_SRC0 768000
#define N_DST0 51200
#define FAN0 15
#define N_DST1 5120
#define FAN1 10
#define N_DST2 1024
#define FAN2 5
#define D_IN 128
#define D_HID 256
#define N_CLS 47

#define TILES0 3200     // 51200 / 16 rows per tile
#define GRID0 512       // persistent blocks (2 per CU)

typedef __attribute__((ext_vector_type(4))) float f32x4;
typedef __attribute__((ext_vector_type(8))) short bf16x8;

static __device__ __forceinline__ unsigned pack_bf16(float x, float y) {
    __hip_bfloat16 hx = __float2bfloat16(x);
    __hip_bfloat16 hy = __float2bfloat16(y);
    unsigned short ux = *(unsigned short*)&hx;
    unsigned short uy = *(unsigned short*)&hy;
    return (unsigned)ux | ((unsigned)uy << 16);
}

static __device__ __forceinline__ short f2bf_s(float v) {
    __hip_bfloat16 hb = __float2bfloat16(v);
    return *(short*)&hb;
}

// ---------------- fused layer 0: persistent, double-buffered, B-in-regs ----------
// 512 blocks x 256 thr (4 waves). Wave w owns cols w*64..w*64+63,
// B[4][8] bf16x8 = 128 VGPR resident, loaded DIRECTLY from fp32 W (transpose
// in-kernel; prep kernel eliminated). Also fills its 1/512 slice of Wt1b
// (consumed only by sage1, which launches later -> no race).
// Per tile: 4 phases of { 8 gather loads (t+1) | 8 MFMAs (t) | reduce+pack+ds_write }.
// One barrier/tile. H1 stored as bf16.
__global__ __launch_bounds__(256, 2) void sage0_persist(
    const float* __restrict__ feats, const int* __restrict__ idx0,
    const int* __restrict__ inv,
    const float* __restrict__ Ws0, const float* __restrict__ Wn0,
    const float* __restrict__ Ws1, const float* __restrict__ Wn1,
    const float* __restrict__ bias, unsigned short* __restrict__ H1b,
    __hip_bfloat16* __restrict__ Wt1b)
{
    __shared__ __align__(16) char xs[2][16 * 512];
    __shared__ int sidx[2][256];

    int tid = threadIdx.x;
    int bid = blockIdx.x;
    int w = tid >> 6, l = tid & 63;
    int lq = l & 15, kq = l >> 4;     // GEMM lane mapping
    int rh = l >> 5, q = l & 31;      // gather lane mapping (2 rows / wave-load)

    // indices for tile t0 -> sidx[0]  (slot 15 = self row)
    {
        int r = tid >> 4, j = tid & 15;
        int rv = inv[bid * 16 + r];
        sidx[0][tid] = (j < 15) ? idx0[(size_t)rv * 15 + j] : rv;
    }

    // Wt1b slice: one element per thread (512*256 threads == 131072 elements).
    // Layout: Wt1b[n*512 + k], k<256 -> Ws1[k][n], else Wn1[k-256][n].
    {
        int t = bid * 256 + tid;
        int n = t >> 9, k = t & 511;
        float v = (k < 256) ? Ws1[k * 256 + n] : Wn1[(k - 256) * 256 + n];
        Wt1b[t] = __float2bfloat16(v);
    }

    // resident B fragments + bias (cols fixed per lane for whole kernel),
    // transposed load straight from fp32 weights (replaces Wt0b prep).
    // B[nt][ks][e] = bf16( k<128 ? Ws0[k][n] : Wn0[k-128][n] ),
    //   n = w*64+nt*16+lq, k = ks*32+kq*8+e
    bf16x8 B[4][8];
#pragma unroll
    for (int nt = 0; nt < 4; ++nt) {
#pragma unroll
        for (int ks = 0; ks < 8; ++ks) {
            int n = w * 64 + nt * 16 + lq;
            int k0 = ks * 32 + kq * 8;
            bf16x8 bv;
#pragma unroll
            for (int e = 0; e < 8; ++e) {
                int k = k0 + e;
                float v = (k < 128) ? Ws0[k * 256 + n] : Wn0[(k - 128) * 256 + n];
                bv[e] = f2bf_s(v);
            }
            B[nt][ks] = bv;
        }
    }
    float bv[4];
#pragma unroll
    for (int nt = 0; nt < 4; ++nt) bv[nt] = bias[w * 64 + nt * 16 + lq];

    int nIter = (TILES0 - bid + GRID0 - 1) / GRID0;

    __syncthreads();

    int pb = 0;
    for (int i = -1; i < nIter; ++i) {
        int t_cur = bid + i * GRID0;
        int t_nxt = t_cur + GRID0;            // tile being gathered this iter
        bool mv = (i >= 0);                   // MFMA valid
        bool gvv = (t_nxt < TILES0);          // gather valid
        int xb = pb ^ 1;
        const int* sp = sidx[pb];

        f32x4 acc[4];
#pragma unroll
        for (int nt = 0; nt < 4; ++nt) acc[nt] = (f32x4){0.f, 0.f, 0.f, 0.f};

        f32x4 s0 = (f32x4){0.f, 0.f, 0.f, 0.f};
#pragma unroll
        for (int ph = 0; ph < 4; ++ph) {
            int h = ph >> 1, jh = ph & 1;
            int r = w * 4 + h * 2 + rh;       // row this lane gathers
            f32x4 g[8];
            if (gvv) {
                const int* sj = sp + r * 16 + jh * 8;
#pragma unroll
                for (int jj = 0; jj < 8; ++jj)
                    g[jj] = *(const f32x4*)&feats[(size_t)sj[jj] * 128 + q * 4];
            }
            if (mv) {
#pragma unroll
                for (int kss = 0; kss < 2; ++kss) {
                    int ks = ph * 2 + kss;
                    bf16x8 af = *(bf16x8*)(xs[pb] +
                        ((lq * 512 + ks * 64 + kq * 16) ^ ((lq & 7) << 4)));
#pragma unroll
                    for (int nt = 0; nt < 4; ++nt)
                        acc[nt] = __builtin_amdgcn_mfma_f32_16x16x32_bf16(
                            af, B[nt][ks], acc[nt], 0, 0, 0);
                }
            }
            if (gvv) {
                if (jh == 0) {
                    s0 = ((g[0] + g[1]) + (g[2] + g[3])) + ((g[4] + g[5]) + (g[6] + g[7]));
                } else {
                    f32x4 m = s0 + ((g[0] + g[1]) + (g[2] + g[3])) + ((g[4] + g[5]) + g[6]);
                    m *= (1.0f / 15.0f);
                    f32x4 sv = g[7];          // slot 15 = self
                    uint2 ps = {pack_bf16(sv.x, sv.y), pack_bf16(sv.z, sv.w)};
                    uint2 pm = {pack_bf16(m.x, m.y), pack_bf16(m.z, m.w)};
                    int xorv = (r & 7) << 4;
                    *(uint2*)(xs[xb] + ((r * 512 + q * 8) ^ xorv)) = ps;        // k=q*4
                    *(uint2*)(xs[xb] + ((r * 512 + 256 + q * 8) ^ xorv)) = pm;  // k=128+q*4
                }
            }
        }

        if (mv) {
#pragma unroll
            for (int nt = 0; nt < 4; ++nt) {
#pragma unroll
                for (int qd = 0; qd < 4; ++qd) {
                    int row = t_cur * 16 + kq * 4 + qd;
                    float v = fmaxf(acc[nt][qd] + bv[nt], 0.f);
                    __hip_bfloat16 hb = __float2bfloat16(v);
                    H1b[(size_t)row * 256 + w * 64 + nt * 16 + lq] =
                        *(unsigned short*)&hb;
                }
            }
        }

        // indices for t_{i+2} -> sidx[xb] (its previous tile's gather is done)
        int t_n2 = t_nxt + GRID0;
        if (t_n2 < TILES0) {
            int r = tid >> 4, j = tid & 15;
            int rv = inv[t_n2 * 16 + r];
            sidx[xb][tid] = (j < 15) ? idx0[(size_t)rv * 15 + j] : rv;
        }
        __syncthreads();
        pb ^= 1;
    }
}

// ---------------- fused layer 1: bf16 gather + bf16 MFMA ----------------
// 16 dst rows x 256 cols per block, 512 threads (8 waves), grid 320.
// H1 is bf16: self row = direct 16B copy; neighbors unpacked via bit-shift for mean.
__global__ __launch_bounds__(512) void sage1_fused(
    const unsigned short* __restrict__ H1b, const int* __restrict__ idx1,
    const __hip_bfloat16* __restrict__ Wt,
    const float* __restrict__ bias, float* __restrict__ H2)
{
    __shared__ __align__(16) char xs[16 * 1024];
    __shared__ int sidx[16 * 12];

    int tid = threadIdx.x;
    int i0 = blockIdx.x * 16;

    for (int p = tid; p < 16 * 10; p += 512) {
        int r = p / 10, j = p % 10;
        sidx[r * 12 + j] = idx1[(size_t)(i0 + r) * 10 + j];
    }
    __syncthreads();

    int w = tid >> 6;
    int l = tid & 63;
    int rh = l >> 5, q = l & 31;

    // ---- gather: wave w covers rows w*2 (+rh); half-wave per 512B bf16 row ----
    {
        int r = w * 2 + rh;
        const int* sj = sidx + r * 12;
        uint4 sv = *(const uint4*)&H1b[(size_t)(i0 + r) * 256 + q * 8];
        f32x4 a0 = (f32x4){0.f, 0.f, 0.f, 0.f};
        f32x4 a1 = (f32x4){0.f, 0.f, 0.f, 0.f};
#pragma unroll
        for (int j = 0; j < 10; ++j) {
            uint4 nv = *(const uint4*)&H1b[(size_t)sj[j] * 256 + q * 8];
            a0.x += __uint_as_float(nv.x << 16);
            a0.y += __uint_as_float(nv.x & 0xffff0000u);
            a0.z += __uint_as_float(nv.y << 16);
            a0.w += __uint_as_float(nv.y & 0xffff0000u);
            a1.x += __uint_as_float(nv.z << 16);
            a1.y += __uint_as_float(nv.z & 0xffff0000u);
            a1.z += __uint_as_float(nv.w << 16);
            a1.w += __uint_as_float(nv.w & 0xffff0000u);
        }
        a0 *= (1.0f / 10.0f);
        a1 *= (1.0f / 10.0f);
        uint4 pm;
        pm.x = pack_bf16(a0.x, a0.y);
        pm.y = pack_bf16(a0.z, a0.w);
        pm.z = pack_bf16(a1.x, a1.y);
        pm.w = pack_bf16(a1.z, a1.w);
        int xorv = (r & 7) << 4;
        *(uint4*)(xs + ((r * 1024 + q * 16) ^ xorv)) = sv;         // k = q*8
        *(uint4*)(xs + ((r * 1024 + 512 + q * 16) ^ xorv)) = pm;   // k = 256+q*8
    }
    __syncthreads();

    // ---- GEMM: 16 rows, wave w -> cols w*32 .. w*32+31 (2 n-tiles), K=512 ----
    int arow = l & 15;
    int kq = l >> 4;
    int xorv_a = (arow & 7) << 4;

    f32x4 acc[2];
    acc[0] = (f32x4){0.f, 0.f, 0.f, 0.f};
    acc[1] = (f32x4){0.f, 0.f, 0.f, 0.f};

#pragma unroll
    for (int ks = 0; ks < 16; ++ks) {      // K = 512
        bf16x8 afrag = *(bf16x8*)(xs + ((arow * 1024 + ks * 64 + kq * 16) ^ xorv_a));
#pragma unroll
        for (int nt = 0; nt < 2; ++nt) {
            int n = w * 32 + nt * 16 + (l & 15);
            bf16x8 bfrag = *(const bf16x8*)(Wt + (size_t)n * 512 + ks * 32 + kq * 8);
            acc[nt] = __builtin_amdgcn_mfma_f32_16x16x32_bf16(afrag, bfrag, acc[nt], 0, 0, 0);
        }
    }

    int col0 = l & 15;
    int rq = l >> 4;
#pragma unroll
    for (int nt = 0; nt < 2; ++nt) {
        int col = w * 32 + nt * 16 + col0;
        float bvv = bias[col];
#pragma unroll
        for (int qd = 0; qd < 4; ++qd) {
            int row = i0 + rq * 4 + qd;
            H2[(size_t)row * 256 + col] = fmaxf(acc[nt][qd] + bvv, 0.f);
        }
    }
}

// ---------------- layer 2: gather + small GEMM (no relu) ----------------
// 2 dst rows per block (grid 512): halves W2 L2 traffic vs 1-row blocks and
// amortizes each weight load over 2 FMAs. x staged TRANSPOSED in LDS
// ([k][row]) so one broadcast float2 read feeds both rows.
// Reads Ws2/Wn2 directly (wave-uniform select; Wc2 materialization dropped).
__global__ __launch_bounds__(256) void layer2(const float* __restrict__ H2,
                                              const int* __restrict__ idx2,
                                              const float* __restrict__ Ws2,
                                              const float* __restrict__ Wn2,
                                              const float* __restrict__ b2,
                                              float* __restrict__ out)
{
    __shared__ float xsf[512][2];      // [k][row]
    __shared__ float part[4][2][64];   // [kq][row][col]
    int d0 = blockIdx.x * 2;
    int t = threadIdx.x;

#pragma unroll
    for (int rr = 0; rr < 2; ++rr) {
        int d = d0 + rr;
        const int* id = idx2 + (size_t)d * FAN2;
        float self = H2[(size_t)d * 256 + t];
        float a = 0.f;
#pragma unroll
        for (int j = 0; j < FAN2; ++j)
            a += H2[(size_t)id[j] * 256 + t];
        xsf[t][rr] = self;
        xsf[256 + t][rr] = a * (1.0f / FAN2);
    }
    __syncthreads();

    int c = t & 63;
    int kq = t >> 6;                   // == wave id -> uniform branches
    float s0 = 0.f, s1 = 0.f;
    if (c < N_CLS) {
        const float* Wp = (kq < 2) ? Ws2 : Wn2;
        int kb = (kq < 2) ? kq * 128 : kq * 128 - 256;
        int kbase = kq * 128;
#pragma unroll 8
        for (int k = 0; k < 128; ++k) {
            float wv = Wp[(size_t)(kb + k) * N_CLS + c];
            float2 xv = *(const float2*)&xsf[kbase + k][0];
            s0 = fmaf(xv.x, wv, s0);
            s1 = fmaf(xv.y, wv, s1);
        }
    }
    part[kq][0][c] = s0;
    part[kq][1][c] = s1;
    __syncthreads();
    if (t < 128) {
        int rr = t >> 6, cc = t & 63;
        if (cc < N_CLS) {
            float v = part[0][rr][cc] + part[1][rr][cc] + part[2][rr][cc]
                    + part[3][rr][cc] + b2[cc];
            out[(size_t)(d0 + rr) * N_CLS + cc] = v;
        }
    }
}

extern "C" void kernel_launch(void* const* d_in, const int* in_sizes, int n_in,
                              void* d_out, int out_size, void* d_ws, size_t ws_size,
                              hipStream_t stream)
{
    const float* feats = (const float*)d_in[0];
    const float* Ws0 = (const float*)d_in[1];
    const float* Wn0 = (const float*)d_in[2];
    const float* b0  = (const float*)d_in[3];
    const float* Ws1 = (const float*)d_in[4];
    const float* Wn1 = (const float*)d_in[5];
    const float* b1  = (const float*)d_in[6];
    const float* Ws2 = (const float*)d_in[7];
    const float* Wn2 = (const float*)d_in[8];
    const float* b2  = (const float*)d_in[9];
    const int* idx0 = (const int*)d_in[10];
    const int* idx1 = (const int*)d_in[11];
    const int* idx2 = (const int*)d_in[12];
    const int* inv  = (const int*)d_in[13];

    char* ws = (char*)d_ws;
    unsigned short* H1b = (unsigned short*)ws;                       // 51200*256*2 B
    float* H2  = (float*)(ws + (size_t)N_DST0 * 256 * 2);            // 5120*256*4 B
    __hip_bfloat16* Wt1b = (__hip_bfloat16*)(H2 + (size_t)N_DST1 * 256); // 256*512 bf16

    sage0_persist<<<dim3(GRID0), dim3(256), 0, stream>>>(feats, idx0, inv,
                                                         Ws0, Wn0, Ws1, Wn1,
                                                         b0, H1b, Wt1b);
    sage1_fused<<<dim3(N_DST1 / 16), dim3(512), 0, stream>>>(H1b, idx1, Wt1b, b1, H2);
    layer2<<<dim3(N_DST2 / 2), dim3(256), 0, stream>>>(H2, idx2, Ws2, Wn2, b2,
                                                       (float*)d_out);
}

// Round 2
// 117.196 us; speedup vs baseline: 1.1500x; 1.1500x over previous
//
#include <hip/hip_runtime.h>
#include <hip/hip_bf16.h>

#define N_SRC0 768000
#define N_DST0 51200
#define FAN0 15
#define N_DST1 5120
#define FAN1 10
#define N_DST2 1024
#define FAN2 5
#define D_IN 128
#define D_HID 256
#define N_CLS 47

#define TILES0 3200     // 51200 / 16 rows per tile
#define GRID0 512       // persistent blocks (2 per CU)

typedef __attribute__((ext_vector_type(4))) float f32x4;
typedef __attribute__((ext_vector_type(8))) short bf16x8;

static __device__ __forceinline__ unsigned pack_bf16(float x, float y) {
    __hip_bfloat16 hx = __float2bfloat16(x);
    __hip_bfloat16 hy = __float2bfloat16(y);
    unsigned short ux = *(unsigned short*)&hx;
    unsigned short uy = *(unsigned short*)&hy;
    return (unsigned)ux | ((unsigned)uy << 16);
}

// ---------------- weight prep ----------------
// Wc2  fp32 [512][47]  = [W_self2; W_neigh2]
// Wt0b bf16 [256 n][256 k], k<128 -> Ws0[k][n], else Wn0[k-128][n]
// Wt1b bf16 [256 n][512 k], k<256 -> Ws1[k][n], else Wn1[k-256][n]
// Also initializes the sage0 work-stealing counter to GRID0.
__global__ void prep_weights(const float* __restrict__ Ws0, const float* __restrict__ Wn0,
                             const float* __restrict__ Ws1, const float* __restrict__ Wn1,
                             const float* __restrict__ Ws2, const float* __restrict__ Wn2,
                             float* __restrict__ Wc2,
                             __hip_bfloat16* __restrict__ Wt0b,
                             __hip_bfloat16* __restrict__ Wt1b,
                             int* __restrict__ ctr)
{
    int t = blockIdx.x * blockDim.x + threadIdx.x;
    if (t == 0) *ctr = GRID0;       // first GRID0 tiles are statically pre-assigned
    const int n2 = D_HID * N_CLS;   // 12032
    if (t < n2) { Wc2[t] = Ws2[t]; Wc2[n2 + t] = Wn2[t]; }
    if (t < 65536) {
        int n = t >> 8, k = t & 255;
        float v = (k < 128) ? Ws0[k * 256 + n] : Wn0[(k - 128) * 256 + n];
        Wt0b[t] = __float2bfloat16(v);
    }
    if (t < 131072) {
        int n = t >> 9, k = t & 511;
        float v = (k < 256) ? Ws1[k * 256 + n] : Wn1[(k - 256) * 256 + n];
        Wt1b[t] = __float2bfloat16(v);
    }
}

// ---------------- fused layer 0: persistent, double-buffered, B-in-regs ----------
// 512 blocks x 256 thr (4 waves). Wave w owns cols w*64..w*64+63,
// B[4][8] bf16x8 = 128 VGPR resident. Per tile: 4 phases of
// { 8 gather loads (t+1) | 8 MFMAs (t) | reduce+pack+ds_write }. One barrier/tile.
// H1 stored as bf16. Tiles distributed by WORK-STEALING: a global counter is
// popped 2 iterations ahead (snext double-buffered), so the sidx prefetch and
// the one-barrier pipeline are unchanged; removes the 6-vs-7-tile static tail.
__global__ __launch_bounds__(256, 2) void sage0_persist(
    const float* __restrict__ feats, const int* __restrict__ idx0,
    const int* __restrict__ inv, const __hip_bfloat16* __restrict__ Wt,
    const float* __restrict__ bias, unsigned short* __restrict__ H1b,
    int* __restrict__ ctr)
{
    __shared__ __align__(16) char xs[2][16 * 512];
    __shared__ int sidx[2][256];
    __shared__ int snext[2];

    int tid = threadIdx.x;
    int bid = blockIdx.x;
    int w = tid >> 6, l = tid & 63;
    int lq = l & 15, kq = l >> 4;     // GEMM lane mapping
    int rh = l >> 5, q = l & 31;      // gather lane mapping (2 rows / wave-load)

    // resident B fragments + bias (cols fixed per lane for whole kernel)
    bf16x8 B[4][8];
#pragma unroll
    for (int nt = 0; nt < 4; ++nt)
#pragma unroll
        for (int ks = 0; ks < 8; ++ks)
            B[nt][ks] = *(const bf16x8*)(Wt +
                (size_t)(w * 64 + nt * 16 + lq) * 256 + ks * 32 + kq * 8);
    float bv[4];
#pragma unroll
    for (int nt = 0; nt < 4; ++nt) bv[nt] = bias[w * 64 + nt * 16 + lq];

    // indices for first gather tile (= bid) -> sidx[0]  (slot 15 = self row)
    {
        int r = tid >> 4, j = tid & 15;
        int rv = inv[bid * 16 + r];
        sidx[0][tid] = (j < 15) ? idx0[(size_t)rv * 15 + j] : rv;
    }
    if (tid == 0) snext[0] = atomicAdd(ctr, 1);   // tile for the 2nd gather
    __syncthreads();

    int t_cur = -1;        // tile MFMA'd this iteration (xs[pb])
    int t_gat = bid;       // tile gathered this iteration (indices in sidx[pb])
    int pb = 0;
    for (;;) {
        bool mv = (t_cur >= 0 && t_cur < TILES0);
        bool gvv = (t_gat < TILES0);
        if (!mv && !gvv) break;
        int xb = pb ^ 1;
        const int* sp = sidx[pb];

        f32x4 acc[4];
#pragma unroll
        for (int nt = 0; nt < 4; ++nt) acc[nt] = (f32x4){0.f, 0.f, 0.f, 0.f};

        f32x4 s0 = (f32x4){0.f, 0.f, 0.f, 0.f};
#pragma unroll
        for (int ph = 0; ph < 4; ++ph) {
            int h = ph >> 1, jh = ph & 1;
            int r = w * 4 + h * 2 + rh;       // row this lane gathers
            f32x4 g[8];
            if (gvv) {
                const int* sj = sp + r * 16 + jh * 8;
#pragma unroll
                for (int jj = 0; jj < 8; ++jj)
                    g[jj] = *(const f32x4*)&feats[(size_t)sj[jj] * 128 + q * 4];
            }
            if (mv) {
#pragma unroll
                for (int kss = 0; kss < 2; ++kss) {
                    int ks = ph * 2 + kss;
                    bf16x8 af = *(bf16x8*)(xs[pb] +
                        ((lq * 512 + ks * 64 + kq * 16) ^ ((lq & 7) << 4)));
#pragma unroll
                    for (int nt = 0; nt < 4; ++nt)
                        acc[nt] = __builtin_amdgcn_mfma_f32_16x16x32_bf16(
                            af, B[nt][ks], acc[nt], 0, 0, 0);
                }
            }
            if (gvv) {
                if (jh == 0) {
                    s0 = ((g[0] + g[1]) + (g[2] + g[3])) + ((g[4] + g[5]) + (g[6] + g[7]));
                } else {
                    f32x4 m = s0 + ((g[0] + g[1]) + (g[2] + g[3])) + ((g[4] + g[5]) + g[6]);
                    m *= (1.0f / 15.0f);
                    f32x4 sv = g[7];          // slot 15 = self
                    uint2 ps = {pack_bf16(sv.x, sv.y), pack_bf16(sv.z, sv.w)};
                    uint2 pm = {pack_bf16(m.x, m.y), pack_bf16(m.z, m.w)};
                    int xorv = (r & 7) << 4;
                    *(uint2*)(xs[xb] + ((r * 512 + q * 8) ^ xorv)) = ps;        // k=q*4
                    *(uint2*)(xs[xb] + ((r * 512 + 256 + q * 8) ^ xorv)) = pm;  // k=128+q*4
                }
            }
        }

        if (mv) {
#pragma unroll
            for (int nt = 0; nt < 4; ++nt) {
#pragma unroll
                for (int qd = 0; qd < 4; ++qd) {
                    int row = t_cur * 16 + kq * 4 + qd;
                    float v = fmaxf(acc[nt][qd] + bv[nt], 0.f);
                    __hip_bfloat16 hb = __float2bfloat16(v);
                    H1b[(size_t)row * 256 + w * 64 + nt * 16 + lq] =
                        *(unsigned short*)&hb;
                }
            }
        }

        // t_fill was popped last iteration; fill its indices for next iter's gather,
        // and pop the tile after it. snext double-buffer avoids write/read race.
        int t_fill = snext[pb];
        if (tid == 0) snext[xb] = atomicAdd(ctr, 1);
        if (t_fill < TILES0) {
            int r = tid >> 4, j = tid & 15;
            int rv = inv[t_fill * 16 + r];
            sidx[xb][tid] = (j < 15) ? idx0[(size_t)rv * 15 + j] : rv;
        }
        __syncthreads();
        t_cur = t_gat;
        t_gat = t_fill;
        pb ^= 1;
    }
}

// ---------------- fused layer 1: bf16 gather + bf16 MFMA ----------------
// 16 dst rows x 256 cols per block, 512 threads (8 waves), grid 320.
// H1 is bf16: self row = direct 16B copy; neighbors unpacked via bit-shift for mean.
__global__ __launch_bounds__(512) void sage1_fused(
    const unsigned short* __restrict__ H1b, const int* __restrict__ idx1,
    const __hip_bfloat16* __restrict__ Wt,
    const float* __restrict__ bias, float* __restrict__ H2)
{
    __shared__ __align__(16) char xs[16 * 1024];
    __shared__ int sidx[16 * 12];

    int tid = threadIdx.x;
    int i0 = blockIdx.x * 16;

    for (int p = tid; p < 16 * 10; p += 512) {
        int r = p / 10, j = p % 10;
        sidx[r * 12 + j] = idx1[(size_t)(i0 + r) * 10 + j];
    }
    __syncthreads();

    int w = tid >> 6;
    int l = tid & 63;
    int rh = l >> 5, q = l & 31;

    // ---- gather: wave w covers rows w*2 (+rh); half-wave per 512B bf16 row ----
    {
        int r = w * 2 + rh;
        const int* sj = sidx + r * 12;
        uint4 sv = *(const uint4*)&H1b[(size_t)(i0 + r) * 256 + q * 8];
        f32x4 a0 = (f32x4){0.f, 0.f, 0.f, 0.f};
        f32x4 a1 = (f32x4){0.f, 0.f, 0.f, 0.f};
#pragma unroll
        for (int j = 0; j < 10; ++j) {
            uint4 nv = *(const uint4*)&H1b[(size_t)sj[j] * 256 + q * 8];
            a0.x += __uint_as_float(nv.x << 16);
            a0.y += __uint_as_float(nv.x & 0xffff0000u);
            a0.z += __uint_as_float(nv.y << 16);
            a0.w += __uint_as_float(nv.y & 0xffff0000u);
            a1.x += __uint_as_float(nv.z << 16);
            a1.y += __uint_as_float(nv.z & 0xffff0000u);
            a1.z += __uint_as_float(nv.w << 16);
            a1.w += __uint_as_float(nv.w & 0xffff0000u);
        }
        a0 *= (1.0f / 10.0f);
        a1 *= (1.0f / 10.0f);
        uint4 pm;
        pm.x = pack_bf16(a0.x, a0.y);
        pm.y = pack_bf16(a0.z, a0.w);
        pm.z = pack_bf16(a1.x, a1.y);
        pm.w = pack_bf16(a1.z, a1.w);
        int xorv = (r & 7) << 4;
        *(uint4*)(xs + ((r * 1024 + q * 16) ^ xorv)) = sv;         // k = q*8
        *(uint4*)(xs + ((r * 1024 + 512 + q * 16) ^ xorv)) = pm;   // k = 256+q*8
    }
    __syncthreads();

    // ---- GEMM: 16 rows, wave w -> cols w*32 .. w*32+31 (2 n-tiles), K=512 ----
    int arow = l & 15;
    int kq = l >> 4;
    int xorv_a = (arow & 7) << 4;

    f32x4 acc[2];
    acc[0] = (f32x4){0.f, 0.f, 0.f, 0.f};
    acc[1] = (f32x4){0.f, 0.f, 0.f, 0.f};

#pragma unroll
    for (int ks = 0; ks < 16; ++ks) {      // K = 512
        bf16x8 afrag = *(bf16x8*)(xs + ((arow * 1024 + ks * 64 + kq * 16) ^ xorv_a));
#pragma unroll
        for (int nt = 0; nt < 2; ++nt) {
            int n = w * 32 + nt * 16 + (l & 15);
            bf16x8 bfrag = *(const bf16x8*)(Wt + (size_t)n * 512 + ks * 32 + kq * 8);
            acc[nt] = __builtin_amdgcn_mfma_f32_16x16x32_bf16(afrag, bfrag, acc[nt], 0, 0, 0);
        }
    }

    int col0 = l & 15;
    int rq = l >> 4;
#pragma unroll
    for (int nt = 0; nt < 2; ++nt) {
        int col = w * 32 + nt * 16 + col0;
        float bvv = bias[col];
#pragma unroll
        for (int qd = 0; qd < 4; ++qd) {
            int row = i0 + rq * 4 + qd;
            H2[(size_t)row * 256 + col] = fmaxf(acc[nt][qd] + bvv, 0.f);
        }
    }
}

// ---------------- layer 2: gather + small GEMM (no relu) ----------------
// 2 dst rows per block (grid 512): halves Wc2 L2 traffic vs 1-row blocks and
// amortizes each weight load over 2 FMAs (two interleaved dep chains).
// x staged TRANSPOSED in LDS ([k][row]) so one broadcast float2 feeds both rows.
__global__ __launch_bounds__(256) void layer2(const float* __restrict__ H2,
                                              const int* __restrict__ idx2,
                                              const float* __restrict__ Wc2,
                                              const float* __restrict__ b2,
                                              float* __restrict__ out)
{
    __shared__ float xsf[512][2];      // [k][row]
    __shared__ float part[4][2][64];   // [kq][row][col]
    int d0 = blockIdx.x * 2;
    int t = threadIdx.x;

#pragma unroll
    for (int rr = 0; rr < 2; ++rr) {
        int d = d0 + rr;
        const int* id = idx2 + (size_t)d * FAN2;
        float self = H2[(size_t)d * 256 + t];
        float a = 0.f;
#pragma unroll
        for (int j = 0; j < FAN2; ++j)
            a += H2[(size_t)id[j] * 256 + t];
        xsf[t][rr] = self;
        xsf[256 + t][rr] = a * (1.0f / FAN2);
    }
    __syncthreads();

    int c = t & 63;
    int kq = t >> 6;                   // == wave id -> uniform
    float s0 = 0.f, s1 = 0.f;
    if (c < N_CLS) {
        int kbase = kq * 128;
#pragma unroll 8
        for (int k = 0; k < 128; ++k) {
            float wv = Wc2[(size_t)(kbase + k) * N_CLS + c];
            float2 xv = *(const float2*)&xsf[kbase + k][0];
            s0 = fmaf(xv.x, wv, s0);
            s1 = fmaf(xv.y, wv, s1);
        }
    }
    part[kq][0][c] = s0;
    part[kq][1][c] = s1;
    __syncthreads();
    if (t < 128) {
        int rr = t >> 6, cc = t & 63;
        if (cc < N_CLS) {
            float v = part[0][rr][cc] + part[1][rr][cc] + part[2][rr][cc]
                    + part[3][rr][cc] + b2[cc];
            out[(size_t)(d0 + rr) * N_CLS + cc] = v;
        }
    }
}

extern "C" void kernel_launch(void* const* d_in, const int* in_sizes, int n_in,
                              void* d_out, int out_size, void* d_ws, size_t ws_size,
                              hipStream_t stream)
{
    const float* feats = (const float*)d_in[0];
    const float* Ws0 = (const float*)d_in[1];
    const float* Wn0 = (const float*)d_in[2];
    const float* b0  = (const float*)d_in[3];
    const float* Ws1 = (const float*)d_in[4];
    const float* Wn1 = (const float*)d_in[5];
    const float* b1  = (const float*)d_in[6];
    const float* Ws2 = (const float*)d_in[7];
    const float* Wn2 = (const float*)d_in[8];
    const float* b2  = (const float*)d_in[9];
    const int* idx0 = (const int*)d_in[10];
    const int* idx1 = (const int*)d_in[11];
    const int* idx2 = (const int*)d_in[12];
    const int* inv  = (const int*)d_in[13];

    char* ws = (char*)d_ws;
    unsigned short* H1b = (unsigned short*)ws;                       // 51200*256*2 B
    float* H2  = (float*)(ws + (size_t)N_DST0 * 256 * 2);            // 5120*256*4 B
    float* Wc2 = H2 + (size_t)N_DST1 * 256;                          // 2*256*47 f
    __hip_bfloat16* Wt0b = (__hip_bfloat16*)(Wc2 + 2 * D_HID * N_CLS);  // 256*256
    __hip_bfloat16* Wt1b = Wt0b + 256 * 256;                            // 256*512
    int* ctr = (int*)(Wt1b + 256 * 512);                                // 4 B

    prep_weights<<<dim3(512), dim3(256), 0, stream>>>(Ws0, Wn0, Ws1, Wn1, Ws2, Wn2,
                                                      Wc2, Wt0b, Wt1b, ctr);
    sage0_persist<<<dim3(GRID0), dim3(256), 0, stream>>>(feats, idx0, inv, Wt0b,
                                                         b0, H1b, ctr);
    sage1_fused<<<dim3(N_DST1 / 16), dim3(512), 0, stream>>>(H1b, idx1, Wt1b, b1, H2);
    layer2<<<dim3(N_DST2 / 2), dim3(256), 0, stream>>>(H2, idx2, Wc2, b2,
                                                       (float*)d_out);
}

// Round 3
// 109.603 us; speedup vs baseline: 1.2297x; 1.0693x over previous
//
#include <hip/hip_runtime.h>
#include <hip/hip_bf16.h>

#define N_SRC0 768000
#define N_DST0 51200
#define FAN0 15
#define N_DST1 5120
#define FAN1 10
#define N_DST2 1024
#define FAN2 5
#define D_IN 128
#define D_HID 256
#define N_CLS 47

#define TILES0 3200     // 51200 / 16 rows per tile
#define GRID0 512       // persistent blocks (2 per CU)
#define NCHUNK 8        // work-stealing shards (1 per XCD)
#define TPC (TILES0 / NCHUNK)   // 400 tiles per chunk
#define BPC (GRID0 / NCHUNK)    // 64 blocks per chunk

typedef __attribute__((ext_vector_type(4))) float f32x4;
typedef __attribute__((ext_vector_type(8))) short bf16x8;

static __device__ __forceinline__ unsigned pack_bf16(float x, float y) {
    __hip_bfloat16 hx = __float2bfloat16(x);
    __hip_bfloat16 hy = __float2bfloat16(y);
    unsigned short ux = *(unsigned short*)&hx;
    unsigned short uy = *(unsigned short*)&hy;
    return (unsigned)ux | ((unsigned)uy << 16);
}

// ---------------- weight prep ----------------
// Wc2  fp32 [512][47]  = [W_self2; W_neigh2]
// Wt0b bf16 [256 n][256 k], k<128 -> Ws0[k][n], else Wn0[k-128][n]
// Wt1b bf16 [256 n][512 k], k<256 -> Ws1[k][n], else Wn1[k-256][n]
// Also initializes the 8 sharded work-stealing counters (64-int spacing).
__global__ void prep_weights(const float* __restrict__ Ws0, const float* __restrict__ Wn0,
                             const float* __restrict__ Ws1, const float* __restrict__ Wn1,
                             const float* __restrict__ Ws2, const float* __restrict__ Wn2,
                             float* __restrict__ Wc2,
                             __hip_bfloat16* __restrict__ Wt0b,
                             __hip_bfloat16* __restrict__ Wt1b,
                             int* __restrict__ ctr)
{
    int t = blockIdx.x * blockDim.x + threadIdx.x;
    if (t < NCHUNK) ctr[t * 64] = t * TPC + BPC;  // first BPC tiles of each chunk are static
    const int n2 = D_HID * N_CLS;   // 12032
    if (t < n2) { Wc2[t] = Ws2[t]; Wc2[n2 + t] = Wn2[t]; }
    if (t < 65536) {
        int n = t >> 8, k = t & 255;
        float v = (k < 128) ? Ws0[k * 256 + n] : Wn0[(k - 128) * 256 + n];
        Wt0b[t] = __float2bfloat16(v);
    }
    if (t < 131072) {
        int n = t >> 9, k = t & 511;
        float v = (k < 256) ? Ws1[k * 256 + n] : Wn1[(k - 256) * 256 + n];
        Wt1b[t] = __float2bfloat16(v);
    }
}

// ---------------- fused layer 0: persistent, double-buffered, B-in-regs ----------
// 512 blocks x 256 thr (4 waves). Wave w owns cols w*64..w*64+63,
// B[4][8] bf16x8 = 128 VGPR resident. Per tile: 4 phases of
// { 8 gather loads (t+1) | 8 MFMAs (t) | reduce+pack+ds_write }. One barrier/tile.
// H1 stored as bf16. Tile distribution: SHARDED work-stealing — 8 chunks of 400
// tiles, 64 blocks each (chunk = bid&7 matches XCD round-robin so the counter
// line stays in the local XCD L2). The pop is issued at the TOP of the
// iteration (consumed only by an LDS write before the end barrier), so the
// atomic round-trip hides under the tile's gather/MFMA work.
__global__ __launch_bounds__(256, 2) void sage0_persist(
    const float* __restrict__ feats, const int* __restrict__ idx0,
    const int* __restrict__ inv, const __hip_bfloat16* __restrict__ Wt,
    const float* __restrict__ bias, unsigned short* __restrict__ H1b,
    int* __restrict__ ctr)
{
    __shared__ __align__(16) char xs[2][16 * 512];
    __shared__ int sidx[2][256];
    __shared__ int snext[2];

    int tid = threadIdx.x;
    int bid = blockIdx.x;
    int w = tid >> 6, l = tid & 63;
    int lq = l & 15, kq = l >> 4;     // GEMM lane mapping
    int rh = l >> 5, q = l & 31;      // gather lane mapping (2 rows / wave-load)

    int chunk = bid & (NCHUNK - 1);
    int tEnd = (chunk + 1) * TPC;
    int* ctrc = ctr + chunk * 64;

    // resident B fragments + bias (cols fixed per lane for whole kernel)
    bf16x8 B[4][8];
#pragma unroll
    for (int nt = 0; nt < 4; ++nt)
#pragma unroll
        for (int ks = 0; ks < 8; ++ks)
            B[nt][ks] = *(const bf16x8*)(Wt +
                (size_t)(w * 64 + nt * 16 + lq) * 256 + ks * 32 + kq * 8);
    float bv[4];
#pragma unroll
    for (int nt = 0; nt < 4; ++nt) bv[nt] = bias[w * 64 + nt * 16 + lq];

    int t_gat = chunk * TPC + (bid >> 3);   // static first tile of this block

    // indices for first gather tile -> sidx[0]  (slot 15 = self row)
    {
        int r = tid >> 4, j = tid & 15;
        int rv = inv[t_gat * 16 + r];
        sidx[0][tid] = (j < 15) ? idx0[(size_t)rv * 15 + j] : rv;
    }
    if (tid == 0) snext[0] = atomicAdd(ctrc, 1);   // tile for the 2nd gather
    __syncthreads();

    int t_cur = -1;        // tile MFMA'd this iteration (xs[pb]); -1 = none
    int pb = 0;
    for (;;) {
        bool mv = (t_cur >= 0);
        bool gvv = (t_gat < tEnd);
        if (!mv && !gvv) break;
        int xb = pb ^ 1;
        const int* sp = sidx[pb];

        // early pop: result only needed at the LDS write before the barrier,
        // ~a full tile of work below to hide the atomic round-trip.
        int nv = 0;
        if (tid == 0) nv = atomicAdd(ctrc, 1);

        f32x4 acc[4];
#pragma unroll
        for (int nt = 0; nt < 4; ++nt) acc[nt] = (f32x4){0.f, 0.f, 0.f, 0.f};

        f32x4 s0 = (f32x4){0.f, 0.f, 0.f, 0.f};
#pragma unroll
        for (int ph = 0; ph < 4; ++ph) {
            int h = ph >> 1, jh = ph & 1;
            int r = w * 4 + h * 2 + rh;       // row this lane gathers
            f32x4 g[8];
            if (gvv) {
                const int* sj = sp + r * 16 + jh * 8;
#pragma unroll
                for (int jj = 0; jj < 8; ++jj)
                    g[jj] = *(const f32x4*)&feats[(size_t)sj[jj] * 128 + q * 4];
            }
            if (mv) {
#pragma unroll
                for (int kss = 0; kss < 2; ++kss) {
                    int ks = ph * 2 + kss;
                    bf16x8 af = *(bf16x8*)(xs[pb] +
                        ((lq * 512 + ks * 64 + kq * 16) ^ ((lq & 7) << 4)));
#pragma unroll
                    for (int nt = 0; nt < 4; ++nt)
                        acc[nt] = __builtin_amdgcn_mfma_f32_16x16x32_bf16(
                            af, B[nt][ks], acc[nt], 0, 0, 0);
                }
            }
            if (gvv) {
                if (jh == 0) {
                    s0 = ((g[0] + g[1]) + (g[2] + g[3])) + ((g[4] + g[5]) + (g[6] + g[7]));
                } else {
                    f32x4 m = s0 + ((g[0] + g[1]) + (g[2] + g[3])) + ((g[4] + g[5]) + g[6]);
                    m *= (1.0f / 15.0f);
                    f32x4 sv = g[7];          // slot 15 = self
                    uint2 ps = {pack_bf16(sv.x, sv.y), pack_bf16(sv.z, sv.w)};
                    uint2 pm = {pack_bf16(m.x, m.y), pack_bf16(m.z, m.w)};
                    int xorv = (r & 7) << 4;
                    *(uint2*)(xs[xb] + ((r * 512 + q * 8) ^ xorv)) = ps;        // k=q*4
                    *(uint2*)(xs[xb] + ((r * 512 + 256 + q * 8) ^ xorv)) = pm;  // k=128+q*4
                }
            }
        }

        if (mv) {
#pragma unroll
            for (int nt = 0; nt < 4; ++nt) {
#pragma unroll
                for (int qd = 0; qd < 4; ++qd) {
                    int row = t_cur * 16 + kq * 4 + qd;
                    float v = fmaxf(acc[nt][qd] + bv[nt], 0.f);
                    __hip_bfloat16 hb = __float2bfloat16(v);
                    H1b[(size_t)row * 256 + w * 64 + nt * 16 + lq] =
                        *(unsigned short*)&hb;
                }
            }
        }

        // t_fill was popped last iteration; fill its indices for next iter's gather.
        int t_fill = snext[pb];
        if (tid == 0) snext[xb] = nv;
        if (t_fill < tEnd) {
            int r = tid >> 4, j = tid & 15;
            int rv = inv[t_fill * 16 + r];
            sidx[xb][tid] = (j < 15) ? idx0[(size_t)rv * 15 + j] : rv;
        }
        __syncthreads();
        t_cur = gvv ? t_gat : -1;
        t_gat = t_fill;
        pb ^= 1;
    }
}

// ---------------- fused layer 1: bf16 gather + bf16 MFMA ----------------
// 16 dst rows x 256 cols per block, 512 threads (8 waves), grid 320.
// H1 is bf16: self row = direct 16B copy; neighbors unpacked via bit-shift for mean.
__global__ __launch_bounds__(512) void sage1_fused(
    const unsigned short* __restrict__ H1b, const int* __restrict__ idx1,
    const __hip_bfloat16* __restrict__ Wt,
    const float* __restrict__ bias, float* __restrict__ H2)
{
    __shared__ __align__(16) char xs[16 * 1024];
    __shared__ int sidx[16 * 12];

    int tid = threadIdx.x;
    int i0 = blockIdx.x * 16;

    for (int p = tid; p < 16 * 10; p += 512) {
        int r = p / 10, j = p % 10;
        sidx[r * 12 + j] = idx1[(size_t)(i0 + r) * 10 + j];
    }
    __syncthreads();

    int w = tid >> 6;
    int l = tid & 63;
    int rh = l >> 5, q = l & 31;

    // ---- gather: wave w covers rows w*2 (+rh); half-wave per 512B bf16 row ----
    {
        int r = w * 2 + rh;
        const int* sj = sidx + r * 12;
        uint4 sv = *(const uint4*)&H1b[(size_t)(i0 + r) * 256 + q * 8];
        f32x4 a0 = (f32x4){0.f, 0.f, 0.f, 0.f};
        f32x4 a1 = (f32x4){0.f, 0.f, 0.f, 0.f};
#pragma unroll
        for (int j = 0; j < 10; ++j) {
            uint4 nv = *(const uint4*)&H1b[(size_t)sj[j] * 256 + q * 8];
            a0.x += __uint_as_float(nv.x << 16);
            a0.y += __uint_as_float(nv.x & 0xffff0000u);
            a0.z += __uint_as_float(nv.y << 16);
            a0.w += __uint_as_float(nv.y & 0xffff0000u);
            a1.x += __uint_as_float(nv.z << 16);
            a1.y += __uint_as_float(nv.z & 0xffff0000u);
            a1.z += __uint_as_float(nv.w << 16);
            a1.w += __uint_as_float(nv.w & 0xffff0000u);
        }
        a0 *= (1.0f / 10.0f);
        a1 *= (1.0f / 10.0f);
        uint4 pm;
        pm.x = pack_bf16(a0.x, a0.y);
        pm.y = pack_bf16(a0.z, a0.w);
        pm.z = pack_bf16(a1.x, a1.y);
        pm.w = pack_bf16(a1.z, a1.w);
        int xorv = (r & 7) << 4;
        *(uint4*)(xs + ((r * 1024 + q * 16) ^ xorv)) = sv;         // k = q*8
        *(uint4*)(xs + ((r * 1024 + 512 + q * 16) ^ xorv)) = pm;   // k = 256+q*8
    }
    __syncthreads();

    // ---- GEMM: 16 rows, wave w -> cols w*32 .. w*32+31 (2 n-tiles), K=512 ----
    int arow = l & 15;
    int kq = l >> 4;
    int xorv_a = (arow & 7) << 4;

    f32x4 acc[2];
    acc[0] = (f32x4){0.f, 0.f, 0.f, 0.f};
    acc[1] = (f32x4){0.f, 0.f, 0.f, 0.f};

#pragma unroll
    for (int ks = 0; ks < 16; ++ks) {      // K = 512
        bf16x8 afrag = *(bf16x8*)(xs + ((arow * 1024 + ks * 64 + kq * 16) ^ xorv_a));
#pragma unroll
        for (int nt = 0; nt < 2; ++nt) {
            int n = w * 32 + nt * 16 + (l & 15);
            bf16x8 bfrag = *(const bf16x8*)(Wt + (size_t)n * 512 + ks * 32 + kq * 8);
            acc[nt] = __builtin_amdgcn_mfma_f32_16x16x32_bf16(afrag, bfrag, acc[nt], 0, 0, 0);
        }
    }

    int col0 = l & 15;
    int rq = l >> 4;
#pragma unroll
    for (int nt = 0; nt < 2; ++nt) {
        int col = w * 32 + nt * 16 + col0;
        float bvv = bias[col];
#pragma unroll
        for (int qd = 0; qd < 4; ++qd) {
            int row = i0 + rq * 4 + qd;
            H2[(size_t)row * 256 + col] = fmaxf(acc[nt][qd] + bvv, 0.f);
        }
    }
}

// ---------------- layer 2: gather + small GEMM (no relu) ----------------
// 2 dst rows per block (grid 512): halves Wc2 L2 traffic vs 1-row blocks and
// amortizes each weight load over 2 FMAs (two interleaved dep chains).
// x staged TRANSPOSED in LDS ([k][row]) so one broadcast float2 feeds both rows.
__global__ __launch_bounds__(256) void layer2(const float* __restrict__ H2,
                                              const int* __restrict__ idx2,
                                              const float* __restrict__ Wc2,
                                              const float* __restrict__ b2,
                                              float* __restrict__ out)
{
    __shared__ float xsf[512][2];      // [k][row]
    __shared__ float part[4][2][64];   // [kq][row][col]
    int d0 = blockIdx.x * 2;
    int t = threadIdx.x;

#pragma unroll
    for (int rr = 0; rr < 2; ++rr) {
        int d = d0 + rr;
        const int* id = idx2 + (size_t)d * FAN2;
        float self = H2[(size_t)d * 256 + t];
        float a = 0.f;
#pragma unroll
        for (int j = 0; j < FAN2; ++j)
            a += H2[(size_t)id[j] * 256 + t];
        xsf[t][rr] = self;
        xsf[256 + t][rr] = a * (1.0f / FAN2);
    }
    __syncthreads();

    int c = t & 63;
    int kq = t >> 6;                   // == wave id -> uniform
    float s0 = 0.f, s1 = 0.f;
    if (c < N_CLS) {
        int kbase = kq * 128;
#pragma unroll 8
        for (int k = 0; k < 128; ++k) {
            float wv = Wc2[(size_t)(kbase + k) * N_CLS + c];
            float2 xv = *(const float2*)&xsf[kbase + k][0];
            s0 = fmaf(xv.x, wv, s0);
            s1 = fmaf(xv.y, wv, s1);
        }
    }
    part[kq][0][c] = s0;
    part[kq][1][c] = s1;
    __syncthreads();
    if (t < 128) {
        int rr = t >> 6, cc = t & 63;
        if (cc < N_CLS) {
            float v = part[0][rr][cc] + part[1][rr][cc] + part[2][rr][cc]
                    + part[3][rr][cc] + b2[cc];
            out[(size_t)(d0 + rr) * N_CLS + cc] = v;
        }
    }
}

extern "C" void kernel_launch(void* const* d_in, const int* in_sizes, int n_in,
                              void* d_out, int out_size, void* d_ws, size_t ws_size,
                              hipStream_t stream)
{
    const float* feats = (const float*)d_in[0];
    const float* Ws0 = (const float*)d_in[1];
    const float* Wn0 = (const float*)d_in[2];
    const float* b0  = (const float*)d_in[3];
    const float* Ws1 = (const float*)d_in[4];
    const float* Wn1 = (const float*)d_in[5];
    const float* b1  = (const float*)d_in[6];
    const float* Ws2 = (const float*)d_in[7];
    const float* Wn2 = (const float*)d_in[8];
    const float* b2  = (const float*)d_in[9];
    const int* idx0 = (const int*)d_in[10];
    const int* idx1 = (const int*)d_in[11];
    const int* idx2 = (const int*)d_in[12];
    const int* inv  = (const int*)d_in[13];

    char* ws = (char*)d_ws;
    unsigned short* H1b = (unsigned short*)ws;                       // 51200*256*2 B
    float* H2  = (float*)(ws + (size_t)N_DST0 * 256 * 2);            // 5120*256*4 B
    float* Wc2 = H2 + (size_t)N_DST1 * 256;                          // 2*256*47 f
    __hip_bfloat16* Wt0b = (__hip_bfloat16*)(Wc2 + 2 * D_HID * N_CLS);  // 256*256
    __hip_bfloat16* Wt1b = Wt0b + 256 * 256;                            // 256*512
    int* ctr = (int*)(Wt1b + 256 * 512);                                // 8*64 ints

    prep_weights<<<dim3(512), dim3(256), 0, stream>>>(Ws0, Wn0, Ws1, Wn1, Ws2, Wn2,
                                                      Wc2, Wt0b, Wt1b, ctr);
    sage0_persist<<<dim3(GRID0), dim3(256), 0, stream>>>(feats, idx0, inv, Wt0b,
                                                         b0, H1b, ctr);
    sage1_fused<<<dim3(N_DST1 / 16), dim3(512), 0, stream>>>(H1b, idx1, Wt1b, b1, H2);
    layer2<<<dim3(N_DST2 / 2), dim3(256), 0, stream>>>(H2, idx2, Wc2, b2,
                                                       (float*)d_out);
}